// Round 1
// baseline (7251.629 us; speedup 1.0000x reference)
//
#include <hip/hip_runtime.h>
#include <hip/hip_bf16.h>
#include <math.h>

// ---------------- problem constants ----------------
#define NGRP 16     // batch groups (one per batch element)
#define GWG  8      // workgroups per group (= heads)
#define NBLK (NGRP*GWG)
#define NTHR 256
#define TSEQ 48
#define DDIM 256
#define NHEAD 8
#define HDIM 32
#define NLAY 3
#define NOUT 6
#define FFD  1024

// ---------------- ws layout (byte offsets) ----------------
#define CNT_OFF   0u
#define CNT_BYTES 4096u          // 16 counters, 256B apart
#define GRP_OFF   4096u
#define GRP_STRF  2048u          // floats per group block
#define OUTV_F 0                 // [6]  fed-back output
#define A_F    16                // [256] attn-out exchange
#define R_F    272               // [256] residual row exchange
#define F_F    528               // [1024] ff1-out exchange
#define KC_OFF  135168u          // k cache [g*8+s][NLAY][TSEQ][32] f32
#define VC_OFF  2494464u         // v cache same
#define WQKV_OFF 4853760u        // bf16 weight copies start here
#define NQKV 589824u
#define NWO  196608u
#define NF1  786432u
#define NF2  786432u
#define NOP1 32768u
#define NCVT (NQKV+NWO+NF1+NF2+NOP1)

__device__ __forceinline__ float bf2f(unsigned short u) {
  union { unsigned int i; float f; } c; c.i = ((unsigned int)u) << 16; return c.f;
}
__device__ __forceinline__ float gelu_exact(float x) {
  return 0.5f * x * (1.0f + erff(x * 0.70710678118654752f));
}

// ---------------- weight fp32 -> bf16 conversion ----------------
__global__ void convert_bf16(const float* qkv, const float* ow, const float* f1,
                             const float* f2, const float* w1, unsigned char* ws) {
  __hip_bfloat16* dst = (__hip_bfloat16*)(ws + WQKV_OFF);
  size_t stride = (size_t)gridDim.x * blockDim.x;
  for (size_t i = (size_t)blockIdx.x * blockDim.x + threadIdx.x; i < NCVT; i += stride) {
    float v;
    if      (i < NQKV)               v = qkv[i];
    else if (i < NQKV+NWO)           v = ow[i - NQKV];
    else if (i < NQKV+NWO+NF1)       v = f1[i - NQKV - NWO];
    else if (i < NQKV+NWO+NF1+NF2)   v = f2[i - NQKV - NWO - NF1];
    else                             v = w1[i - NQKV - NWO - NF1 - NF2];
    dst[i] = __float2bfloat16(v);
  }
}

struct DecP {
  const float *z_style, *z_skill, *start_token;
  const float *mem_w1, *mem_b1, *mem_ln_g, *mem_ln_b, *mem_w2, *mem_b2;
  const float *emb_w, *emb_b;
  const float *sa_qkv_b, *sa_o_b;
  const float *ca_qkv_w, *ca_qkv_b, *ca_o_w, *ca_o_b;
  const float *ln1_g, *ln1_b, *ln2_g, *ln2_b, *ln3_g, *ln3_b;
  const float *ff1_b, *ff2_b;
  const float *op_b1, *op_w2, *op_b2;
  float* out;
  unsigned char* ws;
};

// persistent incremental decoder: 16 independent groups of 8 WGs.
// group g = blockIdx%16 -> all its WGs land on XCD g%8 under round-robin dispatch.
__global__ __launch_bounds__(NTHR) void decoder_persistent(DecP p) {
  const int blk = blockIdx.x;
  const int g = blk % NGRP;      // batch element
  const int s = blk / NGRP;      // slice / head id 0..7
  const int tid = threadIdx.x;

  unsigned int* cnt = (unsigned int*)(p.ws + CNT_OFF) + (size_t)g * 64;
  float* grp  = (float*)(p.ws + GRP_OFF) + (size_t)g * GRP_STRF;
  float* OUTV = grp + OUTV_F;
  float* Ax   = grp + A_F;
  float* Rx   = grp + R_F;
  float* Fx   = grp + F_F;
  float* kcach = (float*)(p.ws + KC_OFF) + (size_t)(g*GWG + s) * NLAY * TSEQ * HDIM;
  float* vcach = (float*)(p.ws + VC_OFF) + (size_t)(g*GWG + s) * NLAY * TSEQ * HDIM;
  const unsigned short* WQKV = (const unsigned short*)(p.ws + WQKV_OFF);
  const unsigned short* WO   = WQKV + NQKV;
  const unsigned short* WF1  = WO + NWO;
  const unsigned short* WF2  = WF1 + NF1;
  const unsigned short* WOP1 = WF2 + NF2;

  __shared__ float xls[DDIM], x2ls[DDIM], cals[NLAY][DDIM], buf[DDIM], frow[FFD];
  __shared__ float red[2*NTHR];
  __shared__ float qb[HDIM], kb[HDIM], vb[HDIM], ob[HDIM];
  __shared__ float sc[64];
  __shared__ float mv[4];

  // ---- group barrier: monotonic counter, agent scope ----
  unsigned int barcount = 0;
  auto group_barrier = [&]() {
    __syncthreads();
    ++barcount;
    if (tid == 0) {
      __threadfence();
      __hip_atomic_fetch_add(cnt, 1u, __ATOMIC_RELEASE, __HIP_MEMORY_SCOPE_AGENT);
      unsigned int target = (unsigned int)GWG * barcount;
      while (__hip_atomic_load(cnt, __ATOMIC_RELAXED, __HIP_MEMORY_SCOPE_AGENT) < target)
        __builtin_amdgcn_s_sleep(1);
      (void)__hip_atomic_load(cnt, __ATOMIC_ACQUIRE, __HIP_MEMORY_SCOPE_AGENT);
    }
    __syncthreads();
  };

  // ---- block-wide LN stats of value v (one per thread, 256 threads) ----
  auto lnstats = [&](float v, float& m, float& rs) {
    red[tid] = v; red[NTHR + tid] = v * v;
    __syncthreads();
    for (int st = 128; st > 0; st >>= 1) {
      if (tid < st) { red[tid] += red[tid+st]; red[NTHR+tid] += red[NTHR+tid+st]; }
      __syncthreads();
    }
    m = red[0] * (1.0f/256.0f);
    float var = red[NTHR] * (1.0f/256.0f) - m*m;
    rs = rsqrtf(var + 1e-5f);
    __syncthreads();
  };

  // ---- gemv: 32 outputs, K=256 from LDS, bf16 rows, 8 threads/output ----
  auto gemv32_256 = [&](const float* xl, const unsigned short* W, const float* bias, float* outl) {
    int o = tid >> 3, pp = tid & 7;
    const unsigned short* w = W + (size_t)o * 256;
    float acc = 0.f;
    #pragma unroll
    for (int i = 0; i < 8; ++i) {
      int k = (i*8 + pp) * 4;
      ushort4 u = *reinterpret_cast<const ushort4*>(w + k);
      acc += xl[k]*bf2f(u.x) + xl[k+1]*bf2f(u.y) + xl[k+2]*bf2f(u.z) + xl[k+3]*bf2f(u.w);
    }
    red[tid] = acc;
    __syncthreads();
    if (tid < 32) {
      float t0 = bias[tid];
      #pragma unroll
      for (int r = 0; r < 8; ++r) t0 += red[tid*8 + r];
      outl[tid] = t0;
    }
    __syncthreads();
  };

  // =======================================================================
  // Prologue (redundant per WG, no barriers): memory vector + ca constants.
  // Cross-attn K/V rows are identical over T -> softmax uniform -> output = V,
  // independent of Q. So cross-attn == per-(layer,batch) constant vector.
  // =======================================================================
  if (tid < 128) buf[tid] = (tid < 64) ? p.z_style[g*64 + tid] : p.z_skill[g*64 + tid - 64];
  __syncthreads();
  {
    float acc = p.mem_b1[tid];
    const float* w = p.mem_w1 + (size_t)tid * 128;
    for (int k = 0; k < 128; ++k) acc += buf[k] * w[k];
    float m, rs; lnstats(acc, m, rs);
    xls[tid] = gelu_exact((acc - m) * rs * p.mem_ln_g[tid] + p.mem_ln_b[tid]);
    __syncthreads();
    float acc2 = p.mem_b2[tid];
    const float* w2 = p.mem_w2 + (size_t)tid * DDIM;
    for (int k = 0; k < DDIM; ++k) acc2 += xls[k] * w2[k];
    x2ls[tid] = acc2;              // memvec
    __syncthreads();
    for (int l = 0; l < NLAY; ++l) {
      float vv = p.ca_qkv_b[l*768 + 512 + tid];
      const float* wv = p.ca_qkv_w + ((size_t)l*768 + 512 + tid) * DDIM;
      for (int k = 0; k < DDIM; ++k) vv += x2ls[k] * wv[k];
      buf[tid] = vv;
      __syncthreads();
      float cc = p.ca_o_b[l*DDIM + tid];
      const float* wo = p.ca_o_w + ((size_t)l*DDIM + tid) * DDIM;
      for (int k = 0; k < DDIM; ++k) cc += buf[k] * wo[k];
      cals[l][tid] = cc;
      __syncthreads();
    }
  }

  const float SCALE = 0.17677669529663687f;  // 1/sqrt(32)

  // =======================================================================
  // Main autoregressive loop: 13 group barriers per step.
  // =======================================================================
  for (int t = 0; t < TSEQ; ++t) {
    for (int l = 0; l < NLAY; ++l) {
      // ---------- PHASE A: build x (redundant) + qkv(head s) + attention(head s)
      if (l == 0) {
        if (tid < NOUT) sc[tid] = (t == 0) ? p.start_token[tid] : OUTV[tid];
        __syncthreads();
        int i2 = tid >> 1;
        float div = expf(-0.03597789207803196f * (float)(2*i2));
        float ang = (float)t * div;
        float pe = (tid & 1) ? cosf(ang) : sinf(ang);
        float acc = p.emb_b[tid] + pe;
        const float* ew = p.emb_w + (size_t)tid * NOUT;
        #pragma unroll
        for (int j = 0; j < NOUT; ++j) acc += sc[j] * ew[j];
        xls[tid] = acc;
        __syncthreads();
      } else {
        float r = Rx[tid];
        float m, rs; lnstats(r, m, rs);
        xls[tid] = (r - m) * rs * p.ln3_g[(l-1)*DDIM + tid] + p.ln3_b[(l-1)*DDIM + tid];
        __syncthreads();
      }
      const unsigned short* Wl = WQKV + (size_t)l * 768 * 256;
      gemv32_256(xls, Wl + (size_t)(      s*32) * 256, p.sa_qkv_b + l*768 +       s*32, qb);
      gemv32_256(xls, Wl + (size_t)(256 + s*32) * 256, p.sa_qkv_b + l*768 + 256 + s*32, kb);
      gemv32_256(xls, Wl + (size_t)(512 + s*32) * 256, p.sa_qkv_b + l*768 + 512 + s*32, vb);
      float* kcl = kcach + ((size_t)l*TSEQ + t) * HDIM;
      float* vcl = vcach + ((size_t)l*TSEQ + t) * HDIM;
      if (tid < HDIM) { kcl[tid] = kb[tid]; vcl[tid] = vb[tid]; }
      __syncthreads();
      if (tid <= t) {
        const float* kr = (tid == t) ? (const float*)kb : (kcach + ((size_t)l*TSEQ + tid) * HDIM);
        float a = 0.f;
        #pragma unroll
        for (int d = 0; d < HDIM; ++d) a += qb[d] * kr[d];
        sc[tid] = a * SCALE;
      }
      __syncthreads();
      if (tid == 0) { float mx = sc[0]; for (int j = 1; j <= t; ++j) mx = fmaxf(mx, sc[j]); mv[0] = mx; }
      __syncthreads();
      if (tid <= t) sc[tid] = expf(sc[tid] - mv[0]);
      __syncthreads();
      if (tid == 0) { float su = 0.f; for (int j = 0; j <= t; ++j) su += sc[j]; mv[1] = 1.0f/su; }
      __syncthreads();
      if (tid < HDIM) {
        float acc = 0.f;
        for (int j = 0; j < t; ++j) acc += sc[j] * vcach[((size_t)l*TSEQ + j)*HDIM + tid];
        acc += sc[t] * vb[tid];
        Ax[s*HDIM + tid] = acc * mv[1];
      }
      group_barrier();  // 1

      // ---------- PHASE B: o-proj slice; r = x + o
      buf[tid] = Ax[tid];
      __syncthreads();
      gemv32_256(buf, WO + (size_t)l*DDIM*DDIM + (size_t)(s*32) * 256, p.sa_o_b + l*DDIM + s*32, ob);
      if (tid < HDIM) Rx[s*HDIM + tid] = xls[s*HDIM + tid] + ob[tid];
      group_barrier();  // 2

      // ---------- PHASE C: (redundant) ln1 + ca + ln2 -> x2 ; ff1 slice + gelu
      {
        float r = Rx[tid];
        float m, rs; lnstats(r, m, rs);
        float y1 = (r - m) * rs * p.ln1_g[l*DDIM + tid] + p.ln1_b[l*DDIM + tid];
        float z = y1 + cals[l][tid];
        float m2, rs2; lnstats(z, m2, rs2);
        x2ls[tid] = (z - m2) * rs2 * p.ln2_g[l*DDIM + tid] + p.ln2_b[l*DDIM + tid];
      }
      __syncthreads();
      {
        int o = tid >> 1, pp = tid & 1;
        const unsigned short* w = WF1 + (size_t)l*FFD*DDIM + (size_t)(s*128 + o) * 256;
        float acc = 0.f;
        #pragma unroll
        for (int i = 0; i < 32; ++i) {
          int k = (i*2 + pp) * 4;
          ushort4 u = *reinterpret_cast<const ushort4*>(w + k);
          acc += x2ls[k]*bf2f(u.x) + x2ls[k+1]*bf2f(u.y) + x2ls[k+2]*bf2f(u.z) + x2ls[k+3]*bf2f(u.w);
        }
        red[tid] = acc;
        __syncthreads();
        if (tid < 128) {
          float v = red[2*tid] + red[2*tid+1] + p.ff1_b[l*FFD + s*128 + tid];
          Fx[s*128 + tid] = gelu_exact(v);
        }
        __syncthreads();
      }
      group_barrier();  // 3

      // ---------- PHASE D: ff2 slice; r = x2 + ff2
      {
        #pragma unroll
        for (int q4 = 0; q4 < 4; ++q4) frow[q4*NTHR + tid] = Fx[q4*NTHR + tid];
        __syncthreads();
        int o = tid >> 3, pp = tid & 7;
        const unsigned short* w = WF2 + (size_t)l*DDIM*FFD + (size_t)(s*32 + o) * 1024;
        float acc = 0.f;
        #pragma unroll
        for (int i = 0; i < 32; ++i) {
          int k = (i*8 + pp) * 4;
          ushort4 u = *reinterpret_cast<const ushort4*>(w + k);
          acc += frow[k]*bf2f(u.x) + frow[k+1]*bf2f(u.y) + frow[k+2]*bf2f(u.z) + frow[k+3]*bf2f(u.w);
        }
        red[tid] = acc;
        __syncthreads();
        if (tid < 32) {
          float v = p.ff2_b[l*DDIM + s*32 + tid];
          #pragma unroll
          for (int r8 = 0; r8 < 8; ++r8) v += red[tid*8 + r8];
          Rx[s*32 + tid] = x2ls[s*32 + tid] + v;
        }
        __syncthreads();
      }
      group_barrier();  // 4
    }

    // ---------- PHASE E: ln3(layer2) + output head (WG s==0 only)
    if (s == 0) {
      float r = Rx[tid];
      float m, rs; lnstats(r, m, rs);
      xls[tid] = (r - m) * rs * p.ln3_g[2*DDIM + tid] + p.ln3_b[2*DDIM + tid];
      __syncthreads();
      int o = tid >> 1, pp = tid & 1;
      const unsigned short* w = WOP1 + (size_t)o * 256;
      float acc = 0.f;
      #pragma unroll
      for (int i = 0; i < 32; ++i) {
        int k = (i*2 + pp) * 4;
        ushort4 u = *reinterpret_cast<const ushort4*>(w + k);
        acc += xls[k]*bf2f(u.x) + xls[k+1]*bf2f(u.y) + xls[k+2]*bf2f(u.z) + xls[k+3]*bf2f(u.w);
      }
      red[tid] = acc;
      __syncthreads();
      if (tid < 128) frow[tid] = gelu_exact(red[2*tid] + red[2*tid+1] + p.op_b1[tid]);
      __syncthreads();
      if (tid < NOUT) {
        float v = p.op_b2[tid];
        const float* w2 = p.op_w2 + (size_t)tid * 128;
        for (int k = 0; k < 128; ++k) v += frow[k] * w2[k];
        p.out[((size_t)g*TSEQ + t) * NOUT + tid] = v;
        OUTV[tid] = v;
      }
    }
    group_barrier();  // 5 (13th of the step)
  }
}

extern "C" void kernel_launch(void* const* d_in, const int* in_sizes, int n_in,
                              void* d_out, int out_size, void* d_ws, size_t ws_size,
                              hipStream_t stream) {
  const float* const* F = (const float* const*)d_in;
  DecP p;
  p.z_style = F[0]; p.z_skill = F[1]; p.start_token = F[2];
  p.mem_w1 = F[3]; p.mem_b1 = F[4]; p.mem_ln_g = F[5]; p.mem_ln_b = F[6];
  p.mem_w2 = F[7]; p.mem_b2 = F[8]; p.emb_w = F[9]; p.emb_b = F[10];
  const float* sa_qkv_w = F[11]; p.sa_qkv_b = F[12];
  const float* sa_o_w  = F[13]; p.sa_o_b = F[14];
  p.ca_qkv_w = F[15]; p.ca_qkv_b = F[16]; p.ca_o_w = F[17]; p.ca_o_b = F[18];
  p.ln1_g = F[19]; p.ln1_b = F[20]; p.ln2_g = F[21]; p.ln2_b = F[22];
  p.ln3_g = F[23]; p.ln3_b = F[24];
  const float* ff1_w = F[25]; p.ff1_b = F[26];
  const float* ff2_w = F[27]; p.ff2_b = F[28];
  const float* op_w1 = F[29]; p.op_b1 = F[30]; p.op_w2 = F[31]; p.op_b2 = F[32];
  p.out = (float*)d_out;
  p.ws  = (unsigned char*)d_ws;

  hipMemsetAsync((char*)d_ws + CNT_OFF, 0, CNT_BYTES, stream);
  convert_bf16<<<dim3(256), dim3(NTHR), 0, stream>>>(sa_qkv_w, sa_o_w, ff1_w, ff2_w, op_w1,
                                                     (unsigned char*)d_ws);
  decoder_persistent<<<dim3(NBLK), dim3(NTHR), 0, stream>>>(p);
}

// Round 3
// 3465.711 us; speedup vs baseline: 2.0924x; 2.0924x over previous
//
#include <hip/hip_runtime.h>
#include <hip/hip_bf16.h>
#include <math.h>

// ---------------- problem constants ----------------
#define NGRP 16     // batch groups (one per batch element)
#define GWG  8      // workgroups per group (= heads)
#define NBLK (NGRP*GWG)
#define NTHR 512
#define TSEQ 48
#define DDIM 256
#define HDIM 32
#define NLAY 3
#define NOUT 6
#define FFD  1024

// ---------------- ws layout ----------------
#define CNT_OFF   0u
#define CNT_BYTES 4096u          // 16 counters, 256B apart
#define GRP_OFF   4096u
#define GRP_STRF  5120u          // floats per group block
#define OUTV_F 0                 // [6]   fed-back output
#define PO_F   16                // [8*256] oproj partials
#define PF_F   2064              // [8*256] ff2 partials
#define CAL_F  4112              // [3*256] cross-attn constants
#define WB_OFF 331776u           // byte offset of bf16 weights
// element offsets inside bf16 weight region
#define WOFF_QKV 0u
#define WOFF_WOT 589824u
#define WOFF_F1  786432u
#define WOFF_F2  1572864u
#define WOFF_OP1 2359296u
#define NCVT     2392064u

__device__ __forceinline__ float bf2f(unsigned short u) {
  union { unsigned int i; float f; } c; c.i = ((unsigned int)u) << 16; return c.f;
}
__device__ __forceinline__ void bfp(unsigned int u, float& lo, float& hi) {
  union { unsigned int i; float f; } a, b;
  a.i = u << 16; b.i = u & 0xffff0000u; lo = a.f; hi = b.f;
}
__device__ __forceinline__ float gelu_exact(float x) {
  return 0.5f * x * (1.0f + erff(x * 0.70710678118654752f));
}

// ---------------- weight fp32 -> bf16 (WO transposed) ----------------
__global__ void convert_bf16(const float* qkv, const float* ow, const float* f1,
                             const float* f2, const float* w1, unsigned char* ws) {
  __hip_bfloat16* dst = (__hip_bfloat16*)(ws + WB_OFF);
  size_t stride = (size_t)gridDim.x * blockDim.x;
  for (size_t i = (size_t)blockIdx.x * blockDim.x + threadIdx.x; i < NCVT; i += stride) {
    float v;
    if (i < WOFF_WOT) v = qkv[i];
    else if (i < WOFF_F1) {                       // WOt[l][k][o] = WO[l][o][k]
      size_t i2 = i - WOFF_WOT;
      size_t l = i2 / 65536, r = i2 % 65536, k = r >> 8, o = r & 255;
      v = ow[l*65536 + o*256 + k];
    }
    else if (i < WOFF_F2)  v = f1[i - WOFF_F1];
    else if (i < WOFF_OP1) v = f2[i - WOFF_F2];
    else                   v = w1[i - WOFF_OP1];
    dst[i] = __float2bfloat16(v);
  }
}

// ---------------- one-shot per-(g,l) constants: memvec chain + cross-attn const ----
// cross-attn K/V rows identical over T -> softmax uniform -> out = V(memvec): a constant.
__global__ void precompute_ca(const float* zs, const float* zk,
                              const float* mw1, const float* mb1,
                              const float* mlg, const float* mlb,
                              const float* mw2, const float* mb2,
                              const float* cqw, const float* cqb,
                              const float* cow, const float* cob,
                              unsigned char* ws) {
  const int g = blockIdx.x & 15, l = blockIdx.x >> 4;
  const int tid = threadIdx.x;           // 256 threads
  __shared__ float cond[128], h[256], mvv[256], vv[256], lred[16];

  auto lnstat = [&](float v, float& m, float& rs) {
    float a = v, b = v * v;
    #pragma unroll
    for (int off = 32; off; off >>= 1) { a += __shfl_xor(a, off); b += __shfl_xor(b, off); }
    if ((tid & 63) == 0) { lred[tid >> 6] = a; lred[4 + (tid >> 6)] = b; }
    __syncthreads();
    float sa = lred[0]+lred[1]+lred[2]+lred[3];
    float sb = lred[4]+lred[5]+lred[6]+lred[7];
    m = sa * (1.0f/256.0f);
    rs = rsqrtf(sb * (1.0f/256.0f) - m*m + 1e-5f);
    __syncthreads();
  };

  if (tid < 128) cond[tid] = (tid < 64) ? zs[g*64 + tid] : zk[g*64 + tid - 64];
  __syncthreads();
  float acc = mb1[tid];
  { const float* w = mw1 + (size_t)tid * 128;
    for (int k = 0; k < 128; k += 4) {
      float4 q = *(const float4*)(w + k);
      acc += q.x*cond[k] + q.y*cond[k+1] + q.z*cond[k+2] + q.w*cond[k+3];
    } }
  float m, rs; lnstat(acc, m, rs);
  h[tid] = gelu_exact((acc - m) * rs * mlg[tid] + mlb[tid]);
  __syncthreads();
  float a2 = mb2[tid];
  { const float* w = mw2 + (size_t)tid * 256;
    for (int k = 0; k < 256; k += 4) {
      float4 q = *(const float4*)(w + k);
      a2 += q.x*h[k] + q.y*h[k+1] + q.z*h[k+2] + q.w*h[k+3];
    } }
  mvv[tid] = a2;
  __syncthreads();
  float a3 = cqb[l*768 + 512 + tid];
  { const float* w = cqw + ((size_t)l*768 + 512 + tid) * 256;
    for (int k = 0; k < 256; k += 4) {
      float4 q = *(const float4*)(w + k);
      a3 += q.x*mvv[k] + q.y*mvv[k+1] + q.z*mvv[k+2] + q.w*mvv[k+3];
    } }
  vv[tid] = a3;
  __syncthreads();
  float a4 = cob[l*256 + tid];
  { const float* w = cow + ((size_t)l*256 + tid) * 256;
    for (int k = 0; k < 256; k += 4) {
      float4 q = *(const float4*)(w + k);
      a4 += q.x*vv[k] + q.y*vv[k+1] + q.z*vv[k+2] + q.w*vv[k+3];
    } }
  ((float*)(ws + GRP_OFF))[(size_t)g * GRP_STRF + CAL_F + l*256 + tid] = a4;
}

struct DecP {
  const float *start_token, *emb_w, *emb_b;
  const float *sa_qkv_b, *sa_o_b;
  const float *ln1_g, *ln1_b, *ln2_g, *ln2_b, *ln3_g, *ln3_b;
  const float *ff1_b, *ff2_b;
  const float *op_b1, *op_w2, *op_b2;
  float* out;
  unsigned char* ws;
};

// persistent incremental decoder: 16 groups x 8 WGs x 512 threads.
// blocks g+16k land on XCD g%8 under round-robin dispatch -> group-local L2.
__global__ __launch_bounds__(NTHR, 1) void decoder_persistent(DecP p) {
  const int blk = blockIdx.x;
  const int g = blk % NGRP;
  const int s = blk / NGRP;           // head / slice id 0..7
  const int tid = threadIdx.x;

  unsigned int* cnt = (unsigned int*)(p.ws + CNT_OFF) + (size_t)g * 64;
  float* grp  = (float*)(p.ws + GRP_OFF) + (size_t)g * GRP_STRF;
  float* OUTV = grp + OUTV_F;
  float* Po   = grp + PO_F;
  float* Pf   = grp + PF_F;
  const float* CALW = grp + CAL_F;
  const unsigned short* WB  = (const unsigned short*)(p.ws + WB_OFF);
  const unsigned short* WQKV = WB + WOFF_QKV;
  const unsigned short* WOT  = WB + WOFF_WOT;
  const unsigned short* WF1  = WB + WOFF_F1;
  const unsigned short* WF2  = WB + WOFF_F2;
  const unsigned short* WOP1 = WB + WOFF_OP1;

  __shared__ float xls[DDIM], x2ls[DDIM], cals[NLAY][DDIM], fxl[128];
  __shared__ float red[NTHR];
  __shared__ float lred[16];
  __shared__ float qb[HDIM], ah[HDIM];
  __shared__ float sc[64];
  __shared__ float kc[NLAY*TSEQ*33];   // padded stride 33: conflict-free
  __shared__ float vc[NLAY*TSEQ*33];

  // ---- group barrier (round-1 proven): acquire-invalidate makes plain
  // post-barrier loads safe (L1 invalidated CU-wide by the acquire).
  unsigned int barcount = 0;
  auto group_barrier = [&]() {
    __syncthreads();
    ++barcount;
    if (tid == 0) {
      __threadfence();
      __hip_atomic_fetch_add(cnt, 1u, __ATOMIC_RELEASE, __HIP_MEMORY_SCOPE_AGENT);
      unsigned int target = (unsigned int)GWG * barcount;
      while (__hip_atomic_load(cnt, __ATOMIC_RELAXED, __HIP_MEMORY_SCOPE_AGENT) < target)
        __builtin_amdgcn_s_sleep(1);
      (void)__hip_atomic_load(cnt, __ATOMIC_ACQUIRE, __HIP_MEMORY_SCOPE_AGENT);
    }
    __syncthreads();
  };

  // ---- shuffle LN over 256 dims (values in tid<256; others pass 0) ----
  auto lnstats = [&](float v, float& m, float& rs) {
    float a = v, b = v * v;
    #pragma unroll
    for (int off = 32; off; off >>= 1) { a += __shfl_xor(a, off); b += __shfl_xor(b, off); }
    if ((tid & 63) == 0) { lred[tid >> 6] = a; lred[8 + (tid >> 6)] = b; }
    __syncthreads();
    float sa = lred[0]+lred[1]+lred[2]+lred[3]+lred[4]+lred[5]+lred[6]+lred[7];
    float sb = lred[8]+lred[9]+lred[10]+lred[11]+lred[12]+lred[13]+lred[14]+lred[15];
    m = sa * (1.0f/256.0f);
    rs = rsqrtf(sb * (1.0f/256.0f) - m*m + 1e-5f);
    __syncthreads();
  };

  // load cross-attn constants
  if (tid < 256) {
    #pragma unroll
    for (int l = 0; l < NLAY; ++l) cals[l][tid] = CALW[l*256 + tid];
  }
  const float divv = (tid < 256) ? expf(-0.035977892078031968f * (float)(2*(tid>>1))) : 0.f;
  const float SCALE = 0.17677669529663687f;  // 1/sqrt(32)
  __syncthreads();

  for (int t = 0; t < TSEQ; ++t) {
    for (int l = 0; l < NLAY; ++l) {
      // ================= PHASE Q: build x, qkv(own head), attn, oproj partial
      // preload fused q|k|v weight tile into regs (hides under x-build)
      const int olin = tid >> 2, kk = tid & 3;
      uint4 wq[8];
      if (olin < 96) {
        int sect = olin >> 5, o = olin & 31;
        const unsigned short* w = WQKV + ((size_t)l*768 + sect*256 + s*32 + o) * 256 + kk*64;
        #pragma unroll
        for (int i = 0; i < 8; ++i) wq[i] = *(const uint4*)(w + i*8);
      }
      // build x  (l is block-uniform: branches never diverge within a block)
      if (l == 0) {
        if (tid < NOUT) sc[tid] = (t == 0) ? p.start_token[tid] : OUTV[tid];
        __syncthreads();
        if (tid < 256) {
          float ang = (float)t * divv;
          float pe = (tid & 1) ? cosf(ang) : sinf(ang);
          float acc = p.emb_b[tid] + pe;
          const float* ew = p.emb_w + (size_t)tid * NOUT;
          #pragma unroll
          for (int j = 0; j < NOUT; ++j) acc += sc[j] * ew[j];
          xls[tid] = acc;
        }
      } else {
        float r2 = 0.f;
        if (tid < 256) {
          r2 = x2ls[tid] + p.ff2_b[(l-1)*256 + tid];
          #pragma unroll
          for (int ss = 0; ss < GWG; ++ss) r2 += Pf[ss*256 + tid];
        }
        float m, rs; lnstats(r2, m, rs);
        if (tid < 256)
          xls[tid] = (r2 - m) * rs * p.ln3_g[(l-1)*256 + tid] + p.ln3_b[(l-1)*256 + tid];
      }
      __syncthreads();
      // qkv accumulate
      if (olin < 96) {
        float acc = 0.f;
        #pragma unroll
        for (int i = 0; i < 8; ++i) {
          int k0 = kk*64 + i*8;
          float lo, hi;
          bfp(wq[i].x, lo, hi); acc += xls[k0  ]*lo + xls[k0+1]*hi;
          bfp(wq[i].y, lo, hi); acc += xls[k0+2]*lo + xls[k0+3]*hi;
          bfp(wq[i].z, lo, hi); acc += xls[k0+4]*lo + xls[k0+5]*hi;
          bfp(wq[i].w, lo, hi); acc += xls[k0+6]*lo + xls[k0+7]*hi;
        }
        red[tid] = acc;
      }
      __syncthreads();
      if (tid < 96) {
        float v = red[tid*4] + red[tid*4+1] + red[tid*4+2] + red[tid*4+3];
        int sect = tid >> 5, o = tid & 31;
        v += p.sa_qkv_b[l*768 + sect*256 + s*32 + o];
        if (sect == 0) qb[o] = v;
        else if (sect == 1) kc[(l*TSEQ + t)*33 + o] = v;
        else vc[(l*TSEQ + t)*33 + o] = v;
      }
      __syncthreads();
      // preload oproj (transposed) column tid: 32 rows -- hidden under attention
      unsigned short wo[32];
      if (tid < 256) {
        const unsigned short* w = WOT + (size_t)l*65536 + (size_t)(s*32)*256 + tid;
        #pragma unroll
        for (int k = 0; k < 32; ++k) wo[k] = w[k*256];
      }
      // attention: scores+softmax in wave 0, PV by 32 lanes
      if (tid < 64) {
        float scj = -1e30f;
        if (tid <= t) {
          const float* kr = &kc[(l*TSEQ + tid)*33];
          float a = 0.f;
          #pragma unroll
          for (int d = 0; d < HDIM; ++d) a += qb[d] * kr[d];
          scj = a * SCALE;
        }
        float mx = scj;
        #pragma unroll
        for (int off = 32; off; off >>= 1) mx = fmaxf(mx, __shfl_xor(mx, off));
        float e = (tid <= t) ? expf(scj - mx) : 0.f;
        float su = e;
        #pragma unroll
        for (int off = 32; off; off >>= 1) su += __shfl_xor(su, off);
        sc[tid] = e / su;
      }
      __syncthreads();
      if (tid < HDIM) {
        float acc = 0.f;
        for (int j = 0; j <= t; ++j) acc += sc[j] * vc[(l*TSEQ + j)*33 + tid];
        ah[tid] = acc;
      }
      __syncthreads();
      // oproj partial (bias added at sum)
      if (tid < 256) {
        float acc = 0.f;
        #pragma unroll
        for (int k = 0; k < 32; ++k) acc += ah[k] * bf2f(wo[k]);
        Po[s*256 + tid] = acc;
      }
      group_barrier();

      // ================= PHASE F: sum+ln1+ca+ln2, ff1(own 128), ff2 partial
      const int o1 = tid >> 2;   // ff1 out 0..127, kk = tid&3
      uint4 wf[8];
      { const unsigned short* w = WF1 + (size_t)l*262144 + (size_t)(s*128 + o1)*256 + kk*64;
        #pragma unroll
        for (int i = 0; i < 8; ++i) wf[i] = *(const uint4*)(w + i*8); }
      float r = 0.f;
      if (tid < 256) {
        r = xls[tid] + p.sa_o_b[l*256 + tid];
        #pragma unroll
        for (int ss = 0; ss < GWG; ++ss) r += Po[ss*256 + tid];
      }
      float m1, rs1; lnstats(r, m1, rs1);
      float z = 0.f;
      if (tid < 256)
        z = (r - m1) * rs1 * p.ln1_g[l*256 + tid] + p.ln1_b[l*256 + tid] + cals[l][tid];
      float m2, rs2; lnstats(z, m2, rs2);
      if (tid < 256)
        x2ls[tid] = (z - m2) * rs2 * p.ln2_g[l*256 + tid] + p.ln2_b[l*256 + tid];
      __syncthreads();
      // ff1
      {
        float acc = 0.f;
        #pragma unroll
        for (int i = 0; i < 8; ++i) {
          int k0 = kk*64 + i*8;
          float lo, hi;
          bfp(wf[i].x, lo, hi); acc += x2ls[k0  ]*lo + x2ls[k0+1]*hi;
          bfp(wf[i].y, lo, hi); acc += x2ls[k0+2]*lo + x2ls[k0+3]*hi;
          bfp(wf[i].z, lo, hi); acc += x2ls[k0+4]*lo + x2ls[k0+5]*hi;
          bfp(wf[i].w, lo, hi); acc += x2ls[k0+6]*lo + x2ls[k0+7]*hi;
        }
        red[tid] = acc;
      }
      // preload ff2 tile (issues while ff1 reduction proceeds)
      const int o2 = tid >> 1, k2 = tid & 1;   // 256 outs, K-half 64
      uint4 wf2[8];
      { const unsigned short* w = WF2 + (size_t)l*262144 + (size_t)o2*1024 + s*128 + k2*64;
        #pragma unroll
        for (int i = 0; i < 8; ++i) wf2[i] = *(const uint4*)(w + i*8); }
      __syncthreads();
      if (tid < 128) {
        float h = red[tid*4] + red[tid*4+1] + red[tid*4+2] + red[tid*4+3]
                + p.ff1_b[l*1024 + s*128 + tid];
        fxl[tid] = gelu_exact(h);
      }
      __syncthreads();
      // ff2 partial
      {
        float acc = 0.f;
        #pragma unroll
        for (int i = 0; i < 8; ++i) {
          int k0 = k2*64 + i*8;
          float lo, hi;
          bfp(wf2[i].x, lo, hi); acc += fxl[k0  ]*lo + fxl[k0+1]*hi;
          bfp(wf2[i].y, lo, hi); acc += fxl[k0+2]*lo + fxl[k0+3]*hi;
          bfp(wf2[i].z, lo, hi); acc += fxl[k0+4]*lo + fxl[k0+5]*hi;
          bfp(wf2[i].w, lo, hi); acc += fxl[k0+6]*lo + fxl[k0+7]*hi;
        }
        red[tid] = acc;
      }
      __syncthreads();
      if (tid < 256) Pf[s*256 + tid] = red[2*tid] + red[2*tid+1];
      group_barrier();
    }

    // ================= PHASE O (s==0): ln3(l2) + output head
    if (s == 0) {
      float r2 = 0.f;
      if (tid < 256) {
        r2 = x2ls[tid] + p.ff2_b[2*256 + tid];
        #pragma unroll
        for (int ss = 0; ss < GWG; ++ss) r2 += Pf[ss*256 + tid];
      }
      float m, rs; lnstats(r2, m, rs);
      if (tid < 256)
        xls[tid] = (r2 - m) * rs * p.ln3_g[2*256 + tid] + p.ln3_b[2*256 + tid];
      __syncthreads();
      const int oo = tid >> 2, kk2 = tid & 3;
      float acc = 0.f;
      { const unsigned short* w = WOP1 + (size_t)oo*256 + kk2*64;
        #pragma unroll
        for (int i = 0; i < 8; ++i) {
          uint4 u = *(const uint4*)(w + i*8);
          int k0 = kk2*64 + i*8;
          float lo, hi;
          bfp(u.x, lo, hi); acc += xls[k0  ]*lo + xls[k0+1]*hi;
          bfp(u.y, lo, hi); acc += xls[k0+2]*lo + xls[k0+3]*hi;
          bfp(u.z, lo, hi); acc += xls[k0+4]*lo + xls[k0+5]*hi;
          bfp(u.w, lo, hi); acc += xls[k0+6]*lo + xls[k0+7]*hi;
        } }
      red[tid] = acc;
      __syncthreads();
      if (tid < 128)
        fxl[tid] = gelu_exact(red[tid*4] + red[tid*4+1] + red[tid*4+2] + red[tid*4+3]
                              + p.op_b1[tid]);
      __syncthreads();
      if (tid < NOUT) {
        float v = p.op_b2[tid];
        const float* w2 = p.op_w2 + (size_t)tid * 128;
        for (int k = 0; k < 128; ++k) v += fxl[k] * w2[k];
        p.out[((size_t)g*TSEQ + t) * NOUT + tid] = v;
        OUTV[tid] = v;
      }
    }
    group_barrier();
  }
}

extern "C" void kernel_launch(void* const* d_in, const int* in_sizes, int n_in,
                              void* d_out, int out_size, void* d_ws, size_t ws_size,
                              hipStream_t stream) {
  const float* const* F = (const float* const*)d_in;
  const float* z_style = F[0]; const float* z_skill = F[1];
  DecP p;
  p.start_token = F[2];
  const float* mem_w1 = F[3]; const float* mem_b1 = F[4];
  const float* mem_ln_g = F[5]; const float* mem_ln_b = F[6];
  const float* mem_w2 = F[7]; const float* mem_b2 = F[8];
  p.emb_w = F[9]; p.emb_b = F[10];
  const float* sa_qkv_w = F[11]; p.sa_qkv_b = F[12];
  const float* sa_o_w  = F[13]; p.sa_o_b = F[14];
  const float* ca_qkv_w = F[15]; const float* ca_qkv_b = F[16];
  const float* ca_o_w = F[17]; const float* ca_o_b = F[18];
  p.ln1_g = F[19]; p.ln1_b = F[20]; p.ln2_g = F[21]; p.ln2_b = F[22];
  p.ln3_g = F[23]; p.ln3_b = F[24];
  const float* ff1_w = F[25]; p.ff1_b = F[26];
  const float* ff2_w = F[27]; p.ff2_b = F[28];
  const float* op_w1 = F[29]; p.op_b1 = F[30]; p.op_w2 = F[31]; p.op_b2 = F[32];
  p.out = (float*)d_out;
  p.ws  = (unsigned char*)d_ws;

  hipMemsetAsync((char*)d_ws + CNT_OFF, 0, CNT_BYTES, stream);
  convert_bf16<<<dim3(256), dim3(256), 0, stream>>>(sa_qkv_w, sa_o_w, ff1_w, ff2_w, op_w1,
                                                    (unsigned char*)d_ws);
  precompute_ca<<<dim3(48), dim3(256), 0, stream>>>(z_style, z_skill, mem_w1, mem_b1,
                                                    mem_ln_g, mem_ln_b, mem_w2, mem_b2,
                                                    ca_qkv_w, ca_qkv_b, ca_o_w, ca_o_b,
                                                    (unsigned char*)d_ws);
  decoder_persistent<<<dim3(NBLK), dim3(NTHR), 0, stream>>>(p);
}